// Round 8
// baseline (636.665 us; speedup 1.0000x reference)
//
#include <hip/hip_runtime.h>
#include <hip/hip_cooperative_groups.h>
#include <math.h>

namespace cg = cooperative_groups;

#define DIM 4096
#define HD 128
#define NH 32
#define NKV 8
#define NCHUNK 128        // chunks per kv head
#define CHUNK 64          // positions per chunk
#define GRID 1024
#define SCALE 0.08838834764831845f  // 1/sqrt(128)

// ============================================================================
// Shared device helpers (used by both the mega-kernel and the fallback path)
// ============================================================================

__device__ __forceinline__ void rope_table_body(int p, const int* start_idx_p,
                                                float* tab)
{
    // numpy-matching f32 semantics: te = fl32(500000^(p/64)); invf = fl32(1/te);
    // freq = fl32(sidx*invf); c,s = fl32(cos/sin(double(freq))).
    const float te   = (float)pow(500000.0, (double)p * (1.0/64.0));
    const float invf = 1.0f / te;
    const float freq = (float)(*start_idx_p) * invf;
    const double ang = (double)freq;
    tab[p]      = (float)cos(ang);
    tab[64 + p] = (float)sin(ang);
}

// One row-pair GEMV + RoPE + scatter. Caller supplies per-block LDS slot.
__device__ __forceinline__ void qkv_pair_body(
    int r0, int wave, int lane, int tid, float dots[4],
    const float* __restrict__ x, const float* __restrict__ wq,
    const float* __restrict__ wk, const float* __restrict__ wv,
    float* __restrict__ k_cache, float* __restrict__ v_cache,
    const int* __restrict__ start_idx_p, const float* __restrict__ tab,
    float* __restrict__ q_buf)
{
    const int rsub = wave >> 1;          // row within pair (0/1)
    const int sub  = wave & 1;           // half of row
    const int rrow = r0 + rsub;
    const float* w;
    if (rrow < DIM)                w = wq + (size_t)rrow * DIM;
    else if (rrow < DIM + NKV*HD)  w = wk + (size_t)(rrow - DIM) * DIM;
    else                           w = wv + (size_t)(rrow - DIM - NKV*HD) * DIM;
    const float4* w4 = (const float4*)w + sub*512;
    const float4* x4 = (const float4*)x + sub*512;
    float acc = 0.f;
#pragma unroll
    for (int it = 0; it < 8; ++it) {
        float4 a = w4[it*64 + lane];
        float4 b = x4[it*64 + lane];
        acc = fmaf(a.x,b.x,acc); acc = fmaf(a.y,b.y,acc);
        acc = fmaf(a.z,b.z,acc); acc = fmaf(a.w,b.w,acc);
    }
#pragma unroll
    for (int off = 32; off > 0; off >>= 1) acc += __shfl_down(acc, off);
    if (lane == 0) dots[wave] = acc;
    __syncthreads();
    if (tid == 0) {
        const float de = dots[0] + dots[1];
        const float dd = dots[2] + dots[3];
        const int sidx = *start_idx_p;
        if (r0 < DIM + NKV*HD) {
            const int local = (r0 < DIM) ? r0 : r0 - DIM;
            const int p = (local & (HD-1)) >> 1;
            const float c = tab[p], s = tab[64 + p];
            const float re = de*c - dd*s;
            const float ro = de*s + dd*c;
            if (r0 < DIM) { q_buf[r0] = re; q_buf[r0+1] = ro; }
            else {
                const size_t base = (size_t)sidx*(NKV*HD) + (size_t)(r0 - DIM);
                k_cache[base] = re; k_cache[base+1] = ro;
            }
        } else {
            const size_t base = (size_t)sidx*(NKV*HD) + (size_t)(r0 - DIM - NKV*HD);
            v_cache[base] = de; v_cache[base+1] = dd;
        }
    }
    __syncthreads();
}

// Flash-decode partial for one (kv, chunk) task. red/lred are LDS.
__device__ __forceinline__ void attn_partial_body(
    int taskid, int wave, int lane, int tid,
    float red[4][4*HD], float lred[4][4],
    const float* __restrict__ q_buf, const float* __restrict__ k_cache,
    const float* __restrict__ v_cache,
    float* __restrict__ part_acc, float* __restrict__ part_l)
{
    const int kv    = taskid >> 7;
    const int chunk = taskid & (NCHUNK-1);
    const int g  = lane >> 4;
    const int gl = lane & 15;

    float4 q0[4], q1[4];
#pragma unroll
    for (int hh = 0; hh < 4; ++hh) {
        const float* qb = q_buf + (size_t)(kv*4 + hh) * HD;
        float4 a = *(const float4*)(qb + gl*4);
        float4 b = *(const float4*)(qb + 64 + gl*4);
        a.x *= SCALE; a.y *= SCALE; a.z *= SCALE; a.w *= SCALE;
        b.x *= SCALE; b.y *= SCALE; b.z *= SCALE; b.w *= SCALE;
        q0[hh] = a; q1[hh] = b;
    }

    float acc0[4][4] = {{0}}, acc1[4][4] = {{0}};
    float lsum[4] = {0.f, 0.f, 0.f, 0.f};

    const int pbase = chunk*CHUNK + wave*16 + g*4;
#pragma unroll
    for (int it = 0; it < 4; it += 2) {
        const int posA = pbase + it, posB = pbase + it + 1;
        const float* kA = k_cache + ((size_t)posA*NKV + kv) * HD;
        const float* kB = k_cache + ((size_t)posB*NKV + kv) * HD;
        float4 k0A = *(const float4*)(kA + gl*4);
        float4 k1A = *(const float4*)(kA + 64 + gl*4);
        float4 k0B = *(const float4*)(kB + gl*4);
        float4 k1B = *(const float4*)(kB + 64 + gl*4);
        float sA[4], sB[4];
#pragma unroll
        for (int hh = 0; hh < 4; ++hh) {
            float t1;
            t1  = q0[hh].x*k0A.x + q0[hh].y*k0A.y + q0[hh].z*k0A.z + q0[hh].w*k0A.w;
            t1 += q1[hh].x*k1A.x + q1[hh].y*k1A.y + q1[hh].z*k1A.z + q1[hh].w*k1A.w;
            sA[hh] = t1;
            t1  = q0[hh].x*k0B.x + q0[hh].y*k0B.y + q0[hh].z*k0B.z + q0[hh].w*k0B.w;
            t1 += q1[hh].x*k1B.x + q1[hh].y*k1B.y + q1[hh].z*k1B.z + q1[hh].w*k1B.w;
            sB[hh] = t1;
        }
#pragma unroll
        for (int off = 1; off < 16; off <<= 1) {
#pragma unroll
            for (int hh = 0; hh < 4; ++hh) {
                sA[hh] += __shfl_xor(sA[hh], off);
                sB[hh] += __shfl_xor(sB[hh], off);
            }
        }
        const float* vA = v_cache + ((size_t)posA*NKV + kv) * HD;
        const float* vB = v_cache + ((size_t)posB*NKV + kv) * HD;
        float4 v0A = *(const float4*)(vA + gl*4);
        float4 v1A = *(const float4*)(vA + 64 + gl*4);
        float4 v0B = *(const float4*)(vB + gl*4);
        float4 v1B = *(const float4*)(vB + 64 + gl*4);
#pragma unroll
        for (int hh = 0; hh < 4; ++hh) {
            const float pA = expf(sA[hh]);
            const float pB = expf(sB[hh]);
            lsum[hh] += pA + pB;
            acc0[hh][0] = fmaf(pA, v0A.x, fmaf(pB, v0B.x, acc0[hh][0]));
            acc0[hh][1] = fmaf(pA, v0A.y, fmaf(pB, v0B.y, acc0[hh][1]));
            acc0[hh][2] = fmaf(pA, v0A.z, fmaf(pB, v0B.z, acc0[hh][2]));
            acc0[hh][3] = fmaf(pA, v0A.w, fmaf(pB, v0B.w, acc0[hh][3]));
            acc1[hh][0] = fmaf(pA, v1A.x, fmaf(pB, v1B.x, acc1[hh][0]));
            acc1[hh][1] = fmaf(pA, v1A.y, fmaf(pB, v1B.y, acc1[hh][1]));
            acc1[hh][2] = fmaf(pA, v1A.z, fmaf(pB, v1B.z, acc1[hh][2]));
            acc1[hh][3] = fmaf(pA, v1A.w, fmaf(pB, v1B.w, acc1[hh][3]));
        }
    }

#pragma unroll
    for (int off = 16; off < 64; off <<= 1) {
#pragma unroll
        for (int hh = 0; hh < 4; ++hh) {
            lsum[hh] += __shfl_xor(lsum[hh], off);
#pragma unroll
            for (int j = 0; j < 4; ++j) {
                acc0[hh][j] += __shfl_xor(acc0[hh][j], off);
                acc1[hh][j] += __shfl_xor(acc1[hh][j], off);
            }
        }
    }

    if (lane < 16) {
#pragma unroll
        for (int hh = 0; hh < 4; ++hh) {
            *(float4*)&red[wave][hh*HD + gl*4] =
                make_float4(acc0[hh][0], acc0[hh][1], acc0[hh][2], acc0[hh][3]);
            *(float4*)&red[wave][hh*HD + 64 + gl*4] =
                make_float4(acc1[hh][0], acc1[hh][1], acc1[hh][2], acc1[hh][3]);
        }
        if (gl == 0) {
            lred[wave][0] = lsum[0]; lred[wave][1] = lsum[1];
            lred[wave][2] = lsum[2]; lred[wave][3] = lsum[3];
        }
    }
    __syncthreads();

    float* outp = part_acc + (size_t)taskid * (4*HD);
#pragma unroll
    for (int k = 0; k < 2; ++k) {
        const int idx = tid + k*256;
        outp[idx] = red[0][idx] + red[1][idx] + red[2][idx] + red[3][idx];
    }
    if (tid < 4) {
        part_l[(size_t)taskid*4 + tid] =
            lred[0][tid] + lred[1][tid] + lred[2][tid] + lred[3][tid];
    }
}

__device__ __forceinline__ void combine_body(
    int taskid, int tid,
    const float* __restrict__ part_acc, const float* __restrict__ part_l,
    float* __restrict__ attn)
{
    const int h  = taskid >> 2;
    const int dq = taskid & 3;
    if (tid < 32) {
        const int d   = dq*32 + tid;
        const int kvh = h >> 2, hh = h & 3;
        float acc = 0.f, l = 0.f;
        for (int c = 0; c < NCHUNK; ++c) {
            const int pid = kvh*NCHUNK + c;
            acc += part_acc[(size_t)pid*(4*HD) + hh*HD + d];
            l   += part_l[pid*4 + hh];
        }
        attn[h*HD + d] = acc / l;
    }
}

__device__ __forceinline__ void out_proj_body(
    int row, int lane, const float* __restrict__ attn,
    const float* __restrict__ wo, float* __restrict__ out)
{
    const float4* w4 = (const float4*)(wo + (size_t)row * DIM);
    const float4* a4 = (const float4*)attn;
    float acc = 0.f;
#pragma unroll
    for (int it = 0; it < 16; ++it) {
        float4 a = w4[it*64 + lane];
        float4 b = a4[it*64 + lane];
        acc = fmaf(a.x,b.x,acc); acc = fmaf(a.y,b.y,acc);
        acc = fmaf(a.z,b.z,acc); acc = fmaf(a.w,b.w,acc);
    }
#pragma unroll
    for (int off = 32; off > 0; off >>= 1) acc += __shfl_down(acc, off);
    if (lane == 0) out[row] = acc;
}

// ============================================================================
// Primary: ONE cooperative kernel, 5 phases separated by grid.sync().
// launch_bounds(256,4): 4 waves/SIMD -> 4 blocks/CU, grid=1024 co-resident.
// ============================================================================
__global__ __launch_bounds__(256, 4) void mha_mega(
    const float* __restrict__ x, const float* __restrict__ wq,
    const float* __restrict__ wk, const float* __restrict__ wv,
    const float* __restrict__ wo,
    float* __restrict__ k_cache, float* __restrict__ v_cache,
    const int* __restrict__ start_idx_p,
    float* __restrict__ q_buf, float* __restrict__ part_acc,
    float* __restrict__ part_l, float* __restrict__ attn,
    float* __restrict__ tab, float* __restrict__ out)
{
    cg::grid_group grid = cg::this_grid();
    const int bid  = blockIdx.x;
    const int tid  = threadIdx.x;
    const int wave = tid >> 6;
    const int lane = tid & 63;

    __shared__ float dots[4];
    __shared__ float red[4][4*HD];
    __shared__ float lred[4][4];

    if (bid == 0 && tid < 64) rope_table_body(tid, start_idx_p, tab);
    grid.sync();

    for (int t = 0; t < 3; ++t)
        qkv_pair_body((bid + t*GRID) * 2, wave, lane, tid, dots,
                      x, wq, wk, wv, k_cache, v_cache, start_idx_p, tab, q_buf);
    grid.sync();

    attn_partial_body(bid, wave, lane, tid, red, lred,
                      q_buf, k_cache, v_cache, part_acc, part_l);
    grid.sync();

    if (bid < 128) combine_body(bid, tid, part_acc, part_l, attn);
    grid.sync();

    out_proj_body(bid*4 + wave, lane, attn, wo, out);
}

// ============================================================================
// Fallback: 5 separate kernels (round-3 proven path), same device bodies.
// ============================================================================
__global__ __launch_bounds__(64) void rope_table_kernel(
    const int* __restrict__ start_idx_p, float* __restrict__ tab)
{
    rope_table_body(threadIdx.x, start_idx_p, tab);
}

__global__ __launch_bounds__(256) void qkv_rope_kernel(
    const float* __restrict__ x, const float* __restrict__ wq,
    const float* __restrict__ wk, const float* __restrict__ wv,
    float* __restrict__ k_cache, float* __restrict__ v_cache,
    const int* __restrict__ start_idx_p, const float* __restrict__ tab,
    float* __restrict__ q_buf)
{
    __shared__ float dots[4];
    qkv_pair_body(blockIdx.x * 2, threadIdx.x >> 6, threadIdx.x & 63,
                  threadIdx.x, dots, x, wq, wk, wv, k_cache, v_cache,
                  start_idx_p, tab, q_buf);
}

__global__ __launch_bounds__(256) void attn_partial_kernel(
    const float* __restrict__ q_buf, const float* __restrict__ k_cache,
    const float* __restrict__ v_cache,
    float* __restrict__ part_acc, float* __restrict__ part_l)
{
    __shared__ float red[4][4*HD];
    __shared__ float lred[4][4];
    attn_partial_body(blockIdx.x, threadIdx.x >> 6, threadIdx.x & 63,
                      threadIdx.x, red, lred, q_buf, k_cache, v_cache,
                      part_acc, part_l);
}

__global__ __launch_bounds__(64) void attn_combine_kernel(
    const float* __restrict__ part_acc, const float* __restrict__ part_l,
    float* __restrict__ attn)
{
    combine_body(blockIdx.x, threadIdx.x, part_acc, part_l, attn);
}

__global__ __launch_bounds__(256) void out_proj_kernel(
    const float* __restrict__ attn, const float* __restrict__ wo,
    float* __restrict__ out)
{
    out_proj_body(blockIdx.x*4 + (threadIdx.x >> 6), threadIdx.x & 63,
                  attn, wo, out);
}

extern "C" void kernel_launch(void* const* d_in, const int* in_sizes, int n_in,
                              void* d_out, int out_size, void* d_ws, size_t ws_size,
                              hipStream_t stream)
{
    const float* x  = (const float*)d_in[0];
    const float* wq = (const float*)d_in[1];
    const float* wk = (const float*)d_in[2];
    const float* wv = (const float*)d_in[3];
    const float* wo = (const float*)d_in[4];
    float* k_cache  = (float*)d_in[5];   // written at [start_idx]; harness restores inputs every launch
    float* v_cache  = (float*)d_in[6];
    const int* sidx = (const int*)d_in[7];
    float* out = (float*)d_out;

    float* ws       = (float*)d_ws;
    float* q_buf    = ws;                          // 4096
    float* part_acc = ws + 4096;                   // 1024 * 512
    float* part_l   = part_acc + 1024*512;         // 4096
    float* attn_buf = part_l + 4096;               // 4096
    float* tab      = attn_buf + 4096;             // 128

    void* args[] = { (void*)&x, (void*)&wq, (void*)&wk, (void*)&wv, (void*)&wo,
                     (void*)&k_cache, (void*)&v_cache, (void*)&sidx,
                     (void*)&q_buf, (void*)&part_acc, (void*)&part_l,
                     (void*)&attn_buf, (void*)&tab, (void*)&out };
    hipError_t err = hipLaunchCooperativeKernel((void*)mha_mega, dim3(GRID),
                                                dim3(256), args, 0, stream);
    if (err != hipSuccess) {
        // Deterministic fallback (coop launch unsupported in this context,
        // e.g. under graph capture): round-3 proven 5-kernel path.
        hipLaunchKernelGGL(rope_table_kernel, dim3(1), dim3(64), 0, stream,
                           sidx, tab);
        hipLaunchKernelGGL(qkv_rope_kernel, dim3((DIM + NKV*HD*2)/2), dim3(256),
                           0, stream, x, wq, wk, wv, k_cache, v_cache, sidx,
                           tab, q_buf);
        hipLaunchKernelGGL(attn_partial_kernel, dim3(NKV*NCHUNK), dim3(256),
                           0, stream, q_buf, k_cache, v_cache, part_acc, part_l);
        hipLaunchKernelGGL(attn_combine_kernel, dim3(NH*4), dim3(64), 0, stream,
                           part_acc, part_l, attn_buf);
        hipLaunchKernelGGL(out_proj_kernel, dim3(DIM/4), dim3(256), 0, stream,
                           attn_buf, wo, out);
    }
}